// Round 3
// baseline (1395.467 us; speedup 1.0000x reference)
//
#include <hip/hip_runtime.h>
#include <hip/hip_bf16.h>

typedef __bf16 bf16_t;
typedef bf16_t bf16x8 __attribute__((ext_vector_type(8)));
typedef float f32x4 __attribute__((ext_vector_type(4)));
typedef unsigned short u16;
typedef unsigned int u32;

static __device__ __forceinline__ u16 f2bf(float f) {
    __hip_bfloat16 h = __float2bfloat16(f);
    return __builtin_bit_cast(u16, h);
}
static __device__ __forceinline__ float bf2f(u16 u) {
    u32 x = ((u32)u) << 16;
    return __builtin_bit_cast(float, x);
}
static __device__ __forceinline__ float lo32(u32 p) { return __builtin_bit_cast(float, p << 16); }
static __device__ __forceinline__ float hi32(u32 p) { return __builtin_bit_cast(float, p & 0xffff0000u); }
static __device__ __forceinline__ float softthr(float v, float l) {
    return copysignf(fmaxf(fabsf(v) - l, 0.0f), v);
}

// ---- prep: Dict copy to out[2], Dnegb = -Dict bf16 [128][512], DictT bf16 [512][128] ----
__global__ __launch_bounds__(256) void prep_dict(const float* __restrict__ Dict,
                                                 float* __restrict__ outd,
                                                 u16* __restrict__ Dnegb,
                                                 u16* __restrict__ DictT)
{
    int i = blockIdx.x * 256 + threadIdx.x;   // 65536 total
    float v = Dict[i];
    outd[i] = v;
    Dnegb[i] = f2bf(-v);
    int d = i >> 9, a = i & 511;
    DictT[(a << 7) + d] = f2bf(v);
}

// ---- fused LISTA, rank-128 factored form ----
// z_{t+1} = ST( z_t + (x - z_t @ Dict^T) @ Dict / L ),  z_0 = ST(x @ Dict)
// GEMM1: acc1 = x + z @ (-Dict^T)   [M=128, N=128, K=512]
// GEMM2: accz += (r) @ Dict          [M=128, N=512, K=128], accz IS fp32 z
__global__ __launch_bounds__(512, 2)
void lista_main(const float* __restrict__ x,
                const float* __restrict__ alpha,
                const float* __restrict__ Lp,
                const int* __restrict__ nip,
                const u16* __restrict__ Dnegb,   // -Dict bf16 [128][512]
                const u16* __restrict__ DictT,   // Dict^T bf16 [512][128]
                float* __restrict__ outz,        // [32][512][1024]
                float* __restrict__ outr)        // [32][128][1024]
{
    __shared__ __align__(16) u16 zl[128 * 512];  // 128 KB: z bf16, swizzled
    __shared__ __align__(16) u16 rl[128 * 128];  // 32 KB: r bf16, swizzled (x at iter 0)

    const int t = threadIdx.x;
    const int lane = t & 63;
    const int l15 = lane & 15;
    const int lg = lane >> 4;          // 0..3
    const int wave = t >> 6;
    const int wm = wave >> 2;          // 0..1 : pixel half
    const int wn = wave & 3;           // 0..3 : col quarter
    const int rb = wm << 6;            // row (pixel) base, both GEMMs
    const int cb1 = wn << 5;           // GEMM1 col base (dims, 32/wave)
    const int cb2 = wn << 7;           // GEMM2 col base (atoms, 128/wave)
    const int bb = blockIdx.x >> 3;
    const int hw0 = (blockIdx.x & 7) << 7;
    const float invL = 1.0f / Lp[0];
    const int niter = nip[0];

    // ---- stage x -> rl bf16 swizzled (this is the iter-0 GEMM2 A operand) ----
    for (int i = t; i < 128 * 128; i += 512) {
        int d = i >> 7, r = i & 127;
        float v = x[((bb * 128 + d) << 10) + hw0 + r];
        rl[((r << 7) + d) ^ ((r & 7) << 3)] = f2bf(v);
    }

    // ---- x register copy at GEMM1 C-tile positions, packed bf16 pairs ----
    u32 xpk[4][2][2];
#pragma unroll
    for (int mt = 0; mt < 4; ++mt)
#pragma unroll
        for (int nt = 0; nt < 2; ++nt) {
            int col = cb1 + nt * 16 + l15;
            const float* xp = &x[((bb * 128 + col) << 10) + hw0 + rb + mt * 16 + lg * 4];
#pragma unroll
            for (int h = 0; h < 2; ++h)
                xpk[mt][nt][h] = (u32)f2bf(xp[h * 2]) | ((u32)f2bf(xp[h * 2 + 1]) << 16);
        }

    // ---- thresholds (alpha/L) for GEMM2 rows, packed bf16 pairs ----
    u32 thp[4][2];
#pragma unroll
    for (int mt = 0; mt < 4; ++mt) {
        const float* ap = &alpha[hw0 + rb + mt * 16 + lg * 4];
#pragma unroll
        for (int h = 0; h < 2; ++h)
            thp[mt][h] = (u32)f2bf(ap[h * 2] * invL) | ((u32)f2bf(ap[h * 2 + 1] * invL) << 16);
    }
    __syncthreads();

    // GEMM1: acc1 = x + z_bf @ (-Dict^T); 1-deep B prefetch
    auto run_gemm1 = [&](f32x4 (&acc1)[4][2]) {
#pragma unroll
        for (int mt = 0; mt < 4; ++mt)
#pragma unroll
            for (int nt = 0; nt < 2; ++nt) {
                acc1[mt][nt][0] = lo32(xpk[mt][nt][0]);
                acc1[mt][nt][1] = hi32(xpk[mt][nt][0]);
                acc1[mt][nt][2] = lo32(xpk[mt][nt][1]);
                acc1[mt][nt][3] = hi32(xpk[mt][nt][1]);
            }
        const u16* b0 = &Dnegb[((cb1 + l15) << 9) + lg * 8];
        bf16x8 Bc0 = *reinterpret_cast<const bf16x8*>(b0);
        bf16x8 Bc1 = *reinterpret_cast<const bf16x8*>(b0 + (16 << 9));
#pragma unroll
        for (int kt = 0; kt < 16; ++kt) {
            const int ktn = (kt < 15) ? kt + 1 : 15;
            bf16x8 Bn0 = *reinterpret_cast<const bf16x8*>(b0 + ktn * 32);
            bf16x8 Bn1 = *reinterpret_cast<const bf16x8*>(b0 + (16 << 9) + ktn * 32);
            bf16x8 Af[4];
            const int k0 = kt * 32 + lg * 8;
#pragma unroll
            for (int mt = 0; mt < 4; ++mt) {
                int row = rb + mt * 16 + l15;
                Af[mt] = *reinterpret_cast<const bf16x8*>(&zl[((row << 9) + k0) ^ ((row & 7) << 3)]);
            }
            __builtin_amdgcn_s_setprio(1);
#pragma unroll
            for (int mt = 0; mt < 4; ++mt) {
                acc1[mt][0] = __builtin_amdgcn_mfma_f32_16x16x32_bf16(Af[mt], Bc0, acc1[mt][0], 0, 0, 0);
                acc1[mt][1] = __builtin_amdgcn_mfma_f32_16x16x32_bf16(Af[mt], Bc1, acc1[mt][1], 0, 0, 0);
            }
            __builtin_amdgcn_s_setprio(0);
            Bc0 = Bn0; Bc1 = Bn1;
        }
    };

    f32x4 accz[4][8];
#pragma unroll
    for (int mt = 0; mt < 4; ++mt)
#pragma unroll
        for (int nt = 0; nt < 8; ++nt)
            accz[mt][nt] = f32x4{0.f, 0.f, 0.f, 0.f};

    for (int it = 0; it <= niter; ++it) {
        if (it > 0) {
            f32x4 acc1[4][2];
            run_gemm1(acc1);
            // r = (x - z@Dict^T)/L = acc1 * invL -> rl
#pragma unroll
            for (int mt = 0; mt < 4; ++mt)
#pragma unroll
                for (int nt = 0; nt < 2; ++nt) {
                    int col = cb1 + nt * 16 + l15;
#pragma unroll
                    for (int rr = 0; rr < 4; ++rr) {
                        int row = rb + mt * 16 + lg * 4 + rr;
                        rl[((row << 7) + col) ^ ((row & 7) << 3)] = f2bf(acc1[mt][nt][rr] * invL);
                    }
                }
            __syncthreads();   // all GEMM1 zl-reads done; rl complete
        }

        // ---- GEMM2: accz += rl @ Dict  (A=rl LDS, B=DictT slice, K=128) ----
        const u16* c0 = &DictT[((cb2 + l15) << 7) + lg * 8];
#pragma unroll
        for (int kt = 0; kt < 4; ++kt) {
            bf16x8 Af[4];
            const int k0 = kt * 32 + lg * 8;
#pragma unroll
            for (int mt = 0; mt < 4; ++mt) {
                int row = rb + mt * 16 + l15;
                Af[mt] = *reinterpret_cast<const bf16x8*>(&rl[((row << 7) + k0) ^ ((row & 7) << 3)]);
            }
            bf16x8 Cf[8];
#pragma unroll
            for (int nt = 0; nt < 8; ++nt)
                Cf[nt] = *reinterpret_cast<const bf16x8*>(c0 + (nt << 11) + kt * 32);
            __builtin_amdgcn_s_setprio(1);
#pragma unroll
            for (int nt = 0; nt < 8; ++nt)
#pragma unroll
                for (int mt = 0; mt < 4; ++mt)
                    accz[mt][nt] = __builtin_amdgcn_mfma_f32_16x16x32_bf16(Af[mt], Cf[nt], accz[mt][nt], 0, 0, 0);
            __builtin_amdgcn_s_setprio(0);
        }

        // ---- soft-threshold in place; write z bf16 to zl ----
#pragma unroll
        for (int mt = 0; mt < 4; ++mt) {
            const float t0 = lo32(thp[mt][0]), t1 = hi32(thp[mt][0]);
            const float t2 = lo32(thp[mt][1]), t3 = hi32(thp[mt][1]);
#pragma unroll
            for (int nt = 0; nt < 8; ++nt) {
                int col = cb2 + nt * 16 + l15;
                f32x4 a = accz[mt][nt];
                a[0] = softthr(a[0], t0);
                a[1] = softthr(a[1], t1);
                a[2] = softthr(a[2], t2);
                a[3] = softthr(a[3], t3);
                accz[mt][nt] = a;
#pragma unroll
                for (int rr = 0; rr < 4; ++rr) {
                    int row = rb + mt * 16 + lg * 4 + rr;
                    zl[((row << 9) + col) ^ ((row & 7) << 3)] = f2bf(a[rr]);
                }
            }
        }
        __syncthreads();
    }

    // ---- final GEMM1: x_recon = z@Dict^T = x - acc1 ----
    f32x4 acc1[4][2];
    run_gemm1(acc1);

    // ---- store z from zl (nontemporal, coalesced) ----
    for (int i = t; i < 128 * 512; i += 512) {
        int a = i >> 7, r = i & 127;
        float zv = bf2f(zl[((r << 9) + a) ^ ((r & 7) << 3)]);
        __builtin_nontemporal_store(zv, &outz[((bb * 512 + a) << 10) + hw0 + r]);
    }
    __syncthreads();   // zl reads done before overwrite

    // ---- stage x_recon fp32 [128][128] swizzled in zl front ----
    float* wf = reinterpret_cast<float*>(zl);
#pragma unroll
    for (int mt = 0; mt < 4; ++mt)
#pragma unroll
        for (int nt = 0; nt < 2; ++nt) {
            int col = cb1 + nt * 16 + l15;
            float xv0 = lo32(xpk[mt][nt][0]), xv1 = hi32(xpk[mt][nt][0]);
            float xv2 = lo32(xpk[mt][nt][1]), xv3 = hi32(xpk[mt][nt][1]);
            f32x4 xr;
            xr[0] = xv0 - acc1[mt][nt][0];
            xr[1] = xv1 - acc1[mt][nt][1];
            xr[2] = xv2 - acc1[mt][nt][2];
            xr[3] = xv3 - acc1[mt][nt][3];
#pragma unroll
            for (int rr = 0; rr < 4; ++rr) {
                int row = rb + mt * 16 + lg * 4 + rr;
                wf[((row << 7) + col) ^ ((row & 7) << 2)] = xr[rr];
            }
        }
    __syncthreads();

    // ---- store x_recon (nontemporal, coalesced) ----
    for (int i = t; i < 128 * 128; i += 512) {
        int d = i >> 7, r = i & 127;
        __builtin_nontemporal_store(wf[((r << 7) + d) ^ ((r & 7) << 2)],
                                    &outr[((bb * 128 + d) << 10) + hw0 + r]);
    }
}

extern "C" void kernel_launch(void* const* d_in, const int* in_sizes, int n_in,
                              void* d_out, int out_size, void* d_ws, size_t ws_size,
                              hipStream_t stream)
{
    const float* x     = (const float*)d_in[0];
    const float* Dict  = (const float*)d_in[1];
    const float* alpha = (const float*)d_in[2];
    const float* Lp    = (const float*)d_in[3];
    const int*   nip   = (const int*)d_in[4];

    float* outz = (float*)d_out;                 // [32,512,32,32]
    float* outr = outz + 32 * 512 * 1024;        // [32,128,32,32]
    float* outd = outr + 32 * 128 * 1024;        // [128,512]

    u16* Dnegb = (u16*)d_ws;                     // 128*512 bf16 = -Dict
    u16* DictT = Dnegb + 128 * 512;              // 512*128 bf16 = Dict^T

    prep_dict<<<dim3(256), dim3(256), 0, stream>>>(Dict, outd, Dnegb, DictT);
    lista_main<<<dim3(256), dim3(512), 0, stream>>>(x, alpha, Lp, nip,
                                                    Dnegb, DictT, outz, outr);
}